// Round 2
// baseline (1367.987 us; speedup 1.0000x reference)
//
#include <hip/hip_runtime.h>
#include <hip/hip_bf16.h>

#define N_NODES 100000
#define D 128
#define E_EDGES 1600000

typedef __attribute__((ext_vector_type(8))) short bf16x8;
typedef __attribute__((ext_vector_type(4))) float f32x4;

__device__ __forceinline__ float bf2f(unsigned short u) {
    unsigned int x = ((unsigned int)u) << 16;
    return __builtin_bit_cast(float, x);
}
__device__ __forceinline__ unsigned short f2bf(float f) {
    unsigned int x = __builtin_bit_cast(unsigned int, f);
    unsigned int lsb = (x >> 16) & 1u;
    x += 0x7fffu + lsb;   // RNE
    return (unsigned short)(x >> 16);
}

// ---------------- Stage 1: LayerNorm  X[N,128] fp32 -> H[N,128] bf16 ----------
// one wave per row; lane handles 2 features
__global__ __launch_bounds__(256) void ln_kernel(
    const float* __restrict__ X,
    const float* __restrict__ gamma,
    const float* __restrict__ beta,
    unsigned short* __restrict__ H)
{
    int wid  = (blockIdx.x * blockDim.x + threadIdx.x) >> 6;
    int lane = threadIdx.x & 63;
    if (wid >= N_NODES) return;

    const float2 x2 = *reinterpret_cast<const float2*>(X + (size_t)wid * D + 2 * lane);
    float x0 = x2.x, x1 = x2.y;
    float s  = x0 + x1;
    float sq = x0 * x0 + x1 * x1;
    #pragma unroll
    for (int m = 1; m < 64; m <<= 1) {
        s  += __shfl_xor(s,  m);
        sq += __shfl_xor(sq, m);
    }
    float mu   = s * (1.0f / 128.0f);
    float var  = sq * (1.0f / 128.0f) - mu * mu;
    float rstd = rsqrtf(var + 1e-5f);

    const float2 g2 = *reinterpret_cast<const float2*>(gamma + 2 * lane);
    const float2 b2 = *reinterpret_cast<const float2*>(beta  + 2 * lane);

    ushort2 h2;
    h2.x = f2bf((x0 - mu) * rstd * g2.x + b2.x);
    h2.y = f2bf((x1 - mu) * rstd * g2.y + b2.y);
    *reinterpret_cast<ushort2*>(H + (size_t)wid * D + 2 * lane) = h2;
}

// ---------------- Stage 2: edge scatter  neigh[dst] += w * H[src] -------------
// one wave per edge (grid-stride); lane handles 2 features; fp32 atomics
__global__ __launch_bounds__(256) void scatter_kernel(
    const unsigned short* __restrict__ H,
    const float* __restrict__ ew,
    const int* __restrict__ esrc,
    const int* __restrict__ edst,
    float* __restrict__ neigh)
{
    int gw   = (blockIdx.x * blockDim.x + threadIdx.x) >> 6;
    int lane = threadIdx.x & 63;
    int nw   = (gridDim.x * blockDim.x) >> 6;
    for (int e = gw; e < E_EDGES; e += nw) {
        int   s = esrc[e];
        int   d = edst[e];
        float w = ew[e];
        ushort2 h2 = *reinterpret_cast<const ushort2*>(H + (size_t)s * D + 2 * lane);
        float* np = neigh + (size_t)d * D + 2 * lane;
        atomicAdd(np,     w * bf2f(h2.x));
        atomicAdd(np + 1, w * bf2f(h2.y));
    }
}

// ---------------- Stage 3: out = relu([H|neigh] @ W + b) + X ------------------
// block = 256 (4 waves). Wave w owns output cols [32w, 32w+32) as 2 MFMA N-tiles.
// B-fragments (W, cast fp32->bf16) held in registers for the whole kernel.
// A (16 rows x 256 k, bf16) staged per strip in XOR-swizzled LDS.
#define ROWS_PER_BLOCK 128
#define STRIPS 8

__global__ __launch_bounds__(256) void gemm_kernel(
    const unsigned short* __restrict__ H,   // [N][128] bf16
    const float* __restrict__ neigh,        // [N][128] fp32
    const float* __restrict__ W,            // [256][128] fp32 row-major
    const float* __restrict__ bias,         // [128] fp32
    const float* __restrict__ X,            // [N][128] fp32
    float* __restrict__ out)                // [N][128] fp32
{
    __shared__ unsigned short lds[16][256];   // 8 KB, rows of 512 B

    const int tid  = threadIdx.x;
    const int w    = tid >> 6;
    const int lane = tid & 63;
    const int l15  = lane & 15;
    const int l4   = lane >> 4;

    // --- load B fragments: b[t][s][j] = bf16(W[32s + 8*l4 + j][32w + 16t + l15])
    bf16x8 bfrag[2][8];
    #pragma unroll
    for (int t = 0; t < 2; ++t) {
        int col = 32 * w + 16 * t + l15;
        #pragma unroll
        for (int s = 0; s < 8; ++s) {
            bf16x8 v;
            #pragma unroll
            for (int j = 0; j < 8; ++j)
                v[j] = (short)f2bf(W[(32 * s + 8 * l4 + j) * D + col]);
            bfrag[t][s] = v;
        }
    }
    const float bias0 = bias[32 * w + l15];
    const float bias1 = bias[32 * w + 16 + l15];

    const int row0_blk = blockIdx.x * ROWS_PER_BLOCK;

    for (int strip = 0; strip < STRIPS; ++strip) {
        const int r0 = row0_blk + strip * 16;
        __syncthreads();   // protect LDS from previous strip's readers

        {   // stage A: 16 rows x 256 cols bf16 (H | bf16(neigh)), XOR-swizzled
            const int row  = tid >> 4;       // 0..15
            const int c8   = tid & 15;       // 16B chunk index
            const int grow = r0 + row;
            char* ldsrow = (char*)&lds[row][0];
            const int key = (row & 7) << 4;

            uint4 hv = make_uint4(0u, 0u, 0u, 0u);
            if (grow < N_NODES)
                hv = *reinterpret_cast<const uint4*>(H + (size_t)grow * D + 8 * c8);
            *reinterpret_cast<uint4*>(ldsrow + ((16 * c8) ^ key)) = hv;

            unsigned short nb[8];
            if (grow < N_NODES) {
                const float* np = neigh + (size_t)grow * D + 8 * c8;
                f32x4 n0 = *reinterpret_cast<const f32x4*>(np);
                f32x4 n1 = *reinterpret_cast<const f32x4*>(np + 4);
                #pragma unroll
                for (int j = 0; j < 4; ++j) { nb[j] = f2bf(n0[j]); nb[4 + j] = f2bf(n1[j]); }
            } else {
                #pragma unroll
                for (int j = 0; j < 8; ++j) nb[j] = 0;
            }
            *reinterpret_cast<uint4*>(ldsrow + ((256 + 16 * c8) ^ key)) =
                *reinterpret_cast<uint4*>(nb);
        }
        __syncthreads();

        f32x4 acc0 = {0.f, 0.f, 0.f, 0.f};
        f32x4 acc1 = {0.f, 0.f, 0.f, 0.f};
        const char* ldsa = (const char*)&lds[l15][0];
        const int   akey = (l15 & 7) << 4;
        #pragma unroll
        for (int s = 0; s < 8; ++s) {
            bf16x8 afrag = *reinterpret_cast<const bf16x8*>(
                ldsa + ((64 * s + 16 * l4) ^ akey));
            acc0 = __builtin_amdgcn_mfma_f32_16x16x32_bf16(afrag, bfrag[0][s], acc0, 0, 0, 0);
            acc1 = __builtin_amdgcn_mfma_f32_16x16x32_bf16(afrag, bfrag[1][s], acc1, 0, 0, 0);
        }

        // epilogue: D row = 4*l4 + r, col = 32w + l15 (+16 for tile 1)
        #pragma unroll
        for (int r = 0; r < 4; ++r) {
            const int grow = r0 + 4 * l4 + r;
            if (grow < N_NODES) {
                const size_t base = (size_t)grow * D;
                const int c0 = 32 * w + l15;
                float v0 = acc0[r] + bias0;
                v0 = v0 > 0.f ? v0 : 0.f;
                out[base + c0] = v0 + X[base + c0];
                const int c1 = c0 + 16;
                float v1 = acc1[r] + bias1;
                v1 = v1 > 0.f ? v1 : 0.f;
                out[base + c1] = v1 + X[base + c1];
            }
        }
    }
}

extern "C" void kernel_launch(void* const* d_in, const int* in_sizes, int n_in,
                              void* d_out, int out_size, void* d_ws, size_t ws_size,
                              hipStream_t stream)
{
    const float* X     = (const float*)d_in[0];
    const float* ew    = (const float*)d_in[1];
    const float* W     = (const float*)d_in[2];
    const float* b     = (const float*)d_in[3];
    const float* gamma = (const float*)d_in[4];
    const float* beta  = (const float*)d_in[5];
    const int* esrc = (const int*)d_in[6];
    const int* edst = (const int*)d_in[7];
    float* out = (float*)d_out;

    unsigned short* H = (unsigned short*)d_ws;                       // 25.6 MB bf16
    float* neigh = (float*)((char*)d_ws + (size_t)N_NODES * D * 2);  // 51.2 MB fp32

    hipMemsetAsync(neigh, 0, (size_t)N_NODES * D * sizeof(float), stream);
    ln_kernel<<<N_NODES / 4, 256, 0, stream>>>(X, gamma, beta, H);
    scatter_kernel<<<4096, 256, 0, stream>>>(H, ew, esrc, edst, neigh);
    gemm_kernel<<<(N_NODES + ROWS_PER_BLOCK - 1) / ROWS_PER_BLOCK, 256, 0, stream>>>(
        H, neigh, W, b, X, out);
}

// Round 3
// 343.467 us; speedup vs baseline: 3.9829x; 3.9829x over previous
//
#include <hip/hip_runtime.h>
#include <hip/hip_bf16.h>

#define N_NODES 100000
#define D 128
#define E_EDGES 1600000
#define SCAN_CHUNK 1024
#define NBLK1 ((N_NODES + SCAN_CHUNK - 1) / SCAN_CHUNK)   // 98

typedef __attribute__((ext_vector_type(8))) short bf16x8;
typedef __attribute__((ext_vector_type(4))) float f32x4;

__device__ __forceinline__ float bf2f(unsigned short u) {
    unsigned int x = ((unsigned int)u) << 16;
    return __builtin_bit_cast(float, x);
}
__device__ __forceinline__ unsigned short f2bf(float f) {
    unsigned int x = __builtin_bit_cast(unsigned int, f);
    unsigned int lsb = (x >> 16) & 1u;
    x += 0x7fffu + lsb;   // RNE
    return (unsigned short)(x >> 16);
}

// ---------------- Stage 1: LayerNorm  X[N,128] fp32 -> H[N,128] bf16 ----------
__global__ __launch_bounds__(256) void ln_kernel(
    const float* __restrict__ X,
    const float* __restrict__ gamma,
    const float* __restrict__ beta,
    unsigned short* __restrict__ H)
{
    int wid  = (blockIdx.x * blockDim.x + threadIdx.x) >> 6;
    int lane = threadIdx.x & 63;
    if (wid >= N_NODES) return;

    const float2 x2 = *reinterpret_cast<const float2*>(X + (size_t)wid * D + 2 * lane);
    float x0 = x2.x, x1 = x2.y;
    float s  = x0 + x1;
    float sq = x0 * x0 + x1 * x1;
    #pragma unroll
    for (int m = 1; m < 64; m <<= 1) {
        s  += __shfl_xor(s,  m);
        sq += __shfl_xor(sq, m);
    }
    float mu   = s * (1.0f / 128.0f);
    float var  = sq * (1.0f / 128.0f) - mu * mu;
    float rstd = rsqrtf(var + 1e-5f);

    const float2 g2 = *reinterpret_cast<const float2*>(gamma + 2 * lane);
    const float2 b2 = *reinterpret_cast<const float2*>(beta  + 2 * lane);

    ushort2 h2;
    h2.x = f2bf((x0 - mu) * rstd * g2.x + b2.x);
    h2.y = f2bf((x1 - mu) * rstd * g2.y + b2.y);
    *reinterpret_cast<ushort2*>(H + (size_t)wid * D + 2 * lane) = h2;
}

// ---------------- CSR build: counting sort of edges by dst --------------------
// hist lives in `cursor` (memset to 0 first)
__global__ __launch_bounds__(256) void hist_kernel(
    const int* __restrict__ edst, unsigned int* __restrict__ hist)
{
    int i = blockIdx.x * blockDim.x + threadIdx.x;
    int stride = gridDim.x * blockDim.x;
    for (int e = i; e < E_EDGES; e += stride)
        atomicAdd(&hist[edst[e]], 1u);
}

// block-local exclusive scan over chunks of 1024; block totals -> bsums
__global__ __launch_bounds__(256) void scan_local_kernel(
    const unsigned int* __restrict__ hist,
    unsigned int* __restrict__ offs,
    unsigned int* __restrict__ bsums)
{
    __shared__ unsigned int wtot[4];
    const int t    = threadIdx.x;
    const int lane = t & 63;
    const int wv   = t >> 6;
    const int i0   = blockIdx.x * SCAN_CHUNK + t * 4;

    unsigned int v[4], s = 0;
    #pragma unroll
    for (int j = 0; j < 4; ++j) {
        int i = i0 + j;
        v[j] = (i < N_NODES) ? hist[i] : 0u;
        s += v[j];
    }
    unsigned int inc = s;
    #pragma unroll
    for (int off = 1; off < 64; off <<= 1) {
        unsigned int u = __shfl_up(inc, off);
        if (lane >= off) inc += u;
    }
    if (lane == 63) wtot[wv] = inc;
    __syncthreads();
    unsigned int wbase = 0;
    for (int k = 0; k < wv; ++k) wbase += wtot[k];

    unsigned int run = wbase + inc - s;    // exclusive prefix for this thread
    #pragma unroll
    for (int j = 0; j < 4; ++j) {
        int i = i0 + j;
        if (i < N_NODES) offs[i] = run;
        run += v[j];
    }
    if (t == 255) bsums[blockIdx.x] = wbase + inc;
}

// exclusive scan of <=128 block sums, in place (one wave)
__global__ __launch_bounds__(64) void scan_bsums_kernel(unsigned int* __restrict__ bsums)
{
    const int lane = threadIdx.x;
    unsigned int a0 = (lane < NBLK1) ? bsums[lane] : 0u;
    unsigned int a1 = (lane + 64 < NBLK1) ? bsums[lane + 64] : 0u;
    unsigned int i0 = a0, i1 = a1;
    #pragma unroll
    for (int off = 1; off < 64; off <<= 1) {
        unsigned int u = __shfl_up(i0, off); if (lane >= off) i0 += u;
        unsigned int w = __shfl_up(i1, off); if (lane >= off) i1 += w;
    }
    unsigned int tot0 = __shfl(i0, 63);
    i1 += tot0;
    if (lane < NBLK1) bsums[lane] = i0 - a0;             // exclusive
    if (lane + 64 < NBLK1) bsums[lane + 64] = i1 - a1;
}

// offs[i] += bsums[i>>10]; cursor[i] = offs[i]
__global__ __launch_bounds__(256) void finalize_offs_kernel(
    unsigned int* __restrict__ offs,
    const unsigned int* __restrict__ bsums,
    unsigned int* __restrict__ cursor)
{
    int i = blockIdx.x * blockDim.x + threadIdx.x;
    if (i < N_NODES) {
        unsigned int o = offs[i] + bsums[i >> 10];
        offs[i] = o;
        cursor[i] = o;
    }
}

// bins[pos] = {src, w} grouped by dst
__global__ __launch_bounds__(256) void bin_kernel(
    const int* __restrict__ esrc, const int* __restrict__ edst,
    const float* __restrict__ ew,
    unsigned int* __restrict__ cursor, uint2* __restrict__ bins)
{
    int i = blockIdx.x * blockDim.x + threadIdx.x;
    int stride = gridDim.x * blockDim.x;
    for (int e = i; e < E_EDGES; e += stride) {
        int d = edst[e];
        unsigned int p = atomicAdd(&cursor[d], 1u);
        bins[p] = make_uint2((unsigned int)esrc[e],
                             __builtin_bit_cast(unsigned int, ew[e]));
    }
}

// ---------------- Stage 2': pull-aggregate  nb[i] = sum w * H[src] ------------
// one wave per node; lane handles 2 features; fp32 accum in registers
__global__ __launch_bounds__(256) void aggregate_kernel(
    const unsigned short* __restrict__ H,
    const uint2* __restrict__ bins,
    const unsigned int* __restrict__ offs,
    const unsigned int* __restrict__ cursor,   // post-bin: end offsets
    unsigned short* __restrict__ nb)
{
    int wid  = (blockIdx.x * blockDim.x + threadIdx.x) >> 6;
    int lane = threadIdx.x & 63;
    if (wid >= N_NODES) return;

    unsigned int e  = offs[wid];
    unsigned int e1 = cursor[wid];
    float a0 = 0.f, a1 = 0.f;

    for (; e + 2 <= e1; e += 2) {
        uint2 r0 = bins[e];
        uint2 r1 = bins[e + 1];
        float w0 = __builtin_bit_cast(float, r0.y);
        float w1 = __builtin_bit_cast(float, r1.y);
        ushort2 h0 = *reinterpret_cast<const ushort2*>(H + (size_t)r0.x * D + 2 * lane);
        ushort2 h1 = *reinterpret_cast<const ushort2*>(H + (size_t)r1.x * D + 2 * lane);
        a0 += w0 * bf2f(h0.x) + w1 * bf2f(h1.x);
        a1 += w0 * bf2f(h0.y) + w1 * bf2f(h1.y);
    }
    if (e < e1) {
        uint2 r0 = bins[e];
        float w0 = __builtin_bit_cast(float, r0.y);
        ushort2 h0 = *reinterpret_cast<const ushort2*>(H + (size_t)r0.x * D + 2 * lane);
        a0 += w0 * bf2f(h0.x);
        a1 += w0 * bf2f(h0.y);
    }
    ushort2 o;
    o.x = f2bf(a0);
    o.y = f2bf(a1);
    *reinterpret_cast<ushort2*>(nb + (size_t)wid * D + 2 * lane) = o;
}

// ---------------- Stage 3: out = relu([H|nb] @ W + b) + X ---------------------
#define ROWS_PER_BLOCK 128
#define STRIPS 8

__global__ __launch_bounds__(256) void gemm_kernel(
    const unsigned short* __restrict__ H,   // [N][128] bf16
    const unsigned short* __restrict__ nb,  // [N][128] bf16
    const float* __restrict__ W,            // [256][128] fp32 row-major
    const float* __restrict__ bias,         // [128] fp32
    const float* __restrict__ X,            // [N][128] fp32
    float* __restrict__ out)                // [N][128] fp32
{
    __shared__ unsigned short lds[16][256];   // 8 KB, rows of 512 B

    const int tid  = threadIdx.x;
    const int w    = tid >> 6;
    const int lane = tid & 63;
    const int l15  = lane & 15;
    const int l4   = lane >> 4;

    bf16x8 bfrag[2][8];
    #pragma unroll
    for (int t = 0; t < 2; ++t) {
        int col = 32 * w + 16 * t + l15;
        #pragma unroll
        for (int s = 0; s < 8; ++s) {
            bf16x8 v;
            #pragma unroll
            for (int j = 0; j < 8; ++j)
                v[j] = (short)f2bf(W[(32 * s + 8 * l4 + j) * D + col]);
            bfrag[t][s] = v;
        }
    }
    const float bias0 = bias[32 * w + l15];
    const float bias1 = bias[32 * w + 16 + l15];

    const int row0_blk = blockIdx.x * ROWS_PER_BLOCK;

    for (int strip = 0; strip < STRIPS; ++strip) {
        const int r0 = row0_blk + strip * 16;
        __syncthreads();

        {   // stage A: 16 rows x 256 k bf16 ([H | nb]), XOR-swizzled
            const int row  = tid >> 4;
            const int c8   = tid & 15;
            const int grow = r0 + row;
            char* ldsrow = (char*)&lds[row][0];
            const int key = (row & 7) << 4;

            uint4 hv = make_uint4(0u, 0u, 0u, 0u);
            uint4 nv = make_uint4(0u, 0u, 0u, 0u);
            if (grow < N_NODES) {
                hv = *reinterpret_cast<const uint4*>(H  + (size_t)grow * D + 8 * c8);
                nv = *reinterpret_cast<const uint4*>(nb + (size_t)grow * D + 8 * c8);
            }
            *reinterpret_cast<uint4*>(ldsrow + ((16 * c8) ^ key)) = hv;
            *reinterpret_cast<uint4*>(ldsrow + ((256 + 16 * c8) ^ key)) = nv;
        }
        __syncthreads();

        f32x4 acc0 = {0.f, 0.f, 0.f, 0.f};
        f32x4 acc1 = {0.f, 0.f, 0.f, 0.f};
        const char* ldsa = (const char*)&lds[l15][0];
        const int   akey = (l15 & 7) << 4;
        #pragma unroll
        for (int s = 0; s < 8; ++s) {
            bf16x8 afrag = *reinterpret_cast<const bf16x8*>(
                ldsa + ((64 * s + 16 * l4) ^ akey));
            acc0 = __builtin_amdgcn_mfma_f32_16x16x32_bf16(afrag, bfrag[0][s], acc0, 0, 0, 0);
            acc1 = __builtin_amdgcn_mfma_f32_16x16x32_bf16(afrag, bfrag[1][s], acc1, 0, 0, 0);
        }

        #pragma unroll
        for (int r = 0; r < 4; ++r) {
            const int grow = r0 + 4 * l4 + r;
            if (grow < N_NODES) {
                const size_t base = (size_t)grow * D;
                const int c0 = 32 * w + l15;
                float v0 = acc0[r] + bias0;
                v0 = v0 > 0.f ? v0 : 0.f;
                out[base + c0] = v0 + X[base + c0];
                const int c1 = c0 + 16;
                float v1 = acc1[r] + bias1;
                v1 = v1 > 0.f ? v1 : 0.f;
                out[base + c1] = v1 + X[base + c1];
            }
        }
    }
}

extern "C" void kernel_launch(void* const* d_in, const int* in_sizes, int n_in,
                              void* d_out, int out_size, void* d_ws, size_t ws_size,
                              hipStream_t stream)
{
    const float* X     = (const float*)d_in[0];
    const float* ew    = (const float*)d_in[1];
    const float* W     = (const float*)d_in[2];
    const float* b     = (const float*)d_in[3];
    const float* gamma = (const float*)d_in[4];
    const float* beta  = (const float*)d_in[5];
    const int* esrc = (const int*)d_in[6];
    const int* edst = (const int*)d_in[7];
    float* out = (float*)d_out;

    // workspace layout (all 8B-aligned)
    unsigned short* H  = (unsigned short*)d_ws;                 // 25.6 MB
    unsigned short* nb = H + (size_t)N_NODES * D;               // 25.6 MB
    uint2* bins = (uint2*)(nb + (size_t)N_NODES * D);           // 12.8 MB
    unsigned int* offs   = (unsigned int*)(bins + E_EDGES);     // 400 KB
    unsigned int* cursor = offs + N_NODES;                      // 400 KB
    unsigned int* bsums  = cursor + N_NODES;                    // 512 B

    hipMemsetAsync(cursor, 0, N_NODES * sizeof(unsigned int), stream);
    ln_kernel<<<N_NODES / 4, 256, 0, stream>>>(X, gamma, beta, H);
    hist_kernel<<<2048, 256, 0, stream>>>(edst, cursor);
    scan_local_kernel<<<NBLK1, 256, 0, stream>>>(cursor, offs, bsums);
    scan_bsums_kernel<<<1, 64, 0, stream>>>(bsums);
    finalize_offs_kernel<<<(N_NODES + 255) / 256, 256, 0, stream>>>(offs, bsums, cursor);
    bin_kernel<<<2048, 256, 0, stream>>>(esrc, edst, ew, cursor, bins);
    aggregate_kernel<<<(N_NODES + 3) / 4, 256, 0, stream>>>(H, bins, offs, cursor, nb);
    gemm_kernel<<<(N_NODES + ROWS_PER_BLOCK - 1) / ROWS_PER_BLOCK, 256, 0, stream>>>(
        H, nb, W, b, X, out);
}